// Round 10
// baseline (3093.342 us; speedup 1.0000x reference)
//
#include <hip/hip_runtime.h>
#include <cstdint>
#include <cstddef>

#define NEGV -1000000000.0f

// ---------- fast device math (fp32, argmax-safe) ----------
__device__ __forceinline__ float fsigm(float x) {
  return 1.0f / (1.0f + __expf(-x));
}
__device__ __forceinline__ float ftanh(float x) {
  x = fminf(x, 30.0f);
  const float e = __expf(2.0f * x);
  return (e - 1.0f) / (e + 1.0f);
}

// ---------------------------------------------------------------------------
// Fused setup GEMM: both context projections in one pass (shared A reads).
// grid(256,4): blockIdx.x = M-tile (fast dim) so the 4 N-tiles sharing one
// A-panel land on the same XCD -> L2 hit. Register double-buffered K-loop.
// (verified rounds 3/4/8/9: ~116 us, FETCH 58 MB)
// ---------------------------------------------------------------------------
__global__ __launch_bounds__(256, 2) void gemm2_k(
    const float* __restrict__ A0, const float* __restrict__ W2,
    const float* __restrict__ b2, float* __restrict__ Cg,
    float* __restrict__ Cp)
{
  __shared__ float As[16][136];     // [k][m]
  __shared__ float Ws[2][16][72];   // [s][k][n]
  const int bm = blockIdx.x << 7;   // fast dim
  const int bn = blockIdx.y << 6;
  const int t  = threadIdx.x;
  const int ty = t >> 4, tx = t & 15;
  const int ar = t >> 1, ac = (t & 1) << 3;   // A staging: 2 float4
  const int wr = t >> 2, wc = (t & 3) << 2;   // W staging: 1 float4 per s
  const float* arow = A0 + (size_t)(bm + ar) * 256 + ac;
  const float* w0row = W2 + (size_t)(bn + wr) * 256 + wc;
  const float* w1row = W2 + (size_t)(256 + bn + wr) * 256 + wc;
  float acc[2][8][4] = {};
  float4 a0 = *(const float4*)(arow + 0);
  float4 a1 = *(const float4*)(arow + 4);
  float4 wv0 = *(const float4*)(w0row + 0);
  float4 wv1 = *(const float4*)(w1row + 0);
  for (int k0 = 0; k0 < 256; k0 += 16) {
    As[ac + 0][ar] = a0.x; As[ac + 1][ar] = a0.y; As[ac + 2][ar] = a0.z; As[ac + 3][ar] = a0.w;
    As[ac + 4][ar] = a1.x; As[ac + 5][ar] = a1.y; As[ac + 6][ar] = a1.z; As[ac + 7][ar] = a1.w;
    Ws[0][wc + 0][wr] = wv0.x; Ws[0][wc + 1][wr] = wv0.y;
    Ws[0][wc + 2][wr] = wv0.z; Ws[0][wc + 3][wr] = wv0.w;
    Ws[1][wc + 0][wr] = wv1.x; Ws[1][wc + 1][wr] = wv1.y;
    Ws[1][wc + 2][wr] = wv1.z; Ws[1][wc + 3][wr] = wv1.w;
    __syncthreads();
    if (k0 < 240) {
      a0  = *(const float4*)(arow + k0 + 16);
      a1  = *(const float4*)(arow + k0 + 20);
      wv0 = *(const float4*)(w0row + k0 + 16);
      wv1 = *(const float4*)(w1row + k0 + 16);
    }
#pragma unroll
    for (int k = 0; k < 16; ++k) {
      const float4 a0v = *(const float4*)&As[k][ty << 3];
      const float4 a1v = *(const float4*)&As[k][(ty << 3) + 4];
      const float am[8] = {a0v.x, a0v.y, a0v.z, a0v.w, a1v.x, a1v.y, a1v.z, a1v.w};
#pragma unroll
      for (int s = 0; s < 2; ++s) {
        const float4 wv = *(const float4*)&Ws[s][k][tx << 2];
#pragma unroll
        for (int i = 0; i < 8; ++i) {
          acc[s][i][0] += am[i] * wv.x;
          acc[s][i][1] += am[i] * wv.y;
          acc[s][i][2] += am[i] * wv.z;
          acc[s][i][3] += am[i] * wv.w;
        }
      }
    }
    __syncthreads();
  }
  const int cn = bn + (tx << 2);
  const float4 bg = *(const float4*)(b2 + cn);
  const float4 bp = *(const float4*)(b2 + 256 + cn);
#pragma unroll
  for (int i = 0; i < 8; ++i) {
    const size_t row = ((size_t)(bm + (ty << 3) + i)) << 8;
    float4 o;
    o.x = acc[0][i][0] + bg.x; o.y = acc[0][i][1] + bg.y;
    o.z = acc[0][i][2] + bg.z; o.w = acc[0][i][3] + bg.w;
    *(float4*)(Cg + row + cn) = o;
    o.x = acc[1][i][0] + bp.x; o.y = acc[1][i][1] + bp.y;
    o.z = acc[1][i][2] + bp.z; o.w = acc[1][i][3] + bp.w;
    *(float4*)(Cp + row + cn) = o;
  }
}

// ---------------------------------------------------------------------------
// gates GEMM (M=512, N=1024 interleaved i,f,g,o per unit, K=512 = [x|h])
// + fused LSTM epilogue. BM=16, BN=64, BK=32 -> 512 blocks (2/CU).
// (exact round-2-verified version)
// ---------------------------------------------------------------------------
__global__ __launch_bounds__(256) void gates_lstm_k(
    const float* __restrict__ x, const float* __restrict__ hin,
    const float* __restrict__ Wcat, const float* __restrict__ bcat,
    const float* __restrict__ cin, float* __restrict__ cnew,
    float* __restrict__ hnew)
{
  __shared__ __align__(16) float As[16][36];   // [m][k]
  __shared__ __align__(16) float Ws[32][68];   // [k][n]
  const int bn = blockIdx.x << 6;
  const int bm = blockIdx.y << 4;
  const int t  = threadIdx.x;
  const int ty = t >> 4, tx = t & 15;
  const int ar = t >> 4, ak = (t & 15) << 1;   // A staging: one float2
  const int wr = t >> 2, wk = (t & 3) << 3;    // W staging: two float4
  const float* wrow = Wcat + ((size_t)(bn + wr) << 9);
  const int arow = bm + ar;
  float acc0 = 0.f, acc1 = 0.f, acc2 = 0.f, acc3 = 0.f;
  for (int k0 = 0; k0 < 512; k0 += 32) {
    const int kk = k0 + ak;
    float2 av;
    if (kk < 256) av = *(const float2*)(x   + ((size_t)arow << 8) + kk);
    else          av = *(const float2*)(hin + ((size_t)arow << 8) + (kk - 256));
    const float4 w0 = *(const float4*)(wrow + k0 + wk);
    const float4 w1 = *(const float4*)(wrow + k0 + wk + 4);
    *(float2*)&As[ar][ak] = av;
    Ws[wk + 0][wr] = w0.x; Ws[wk + 1][wr] = w0.y; Ws[wk + 2][wr] = w0.z; Ws[wk + 3][wr] = w0.w;
    Ws[wk + 4][wr] = w1.x; Ws[wk + 5][wr] = w1.y; Ws[wk + 6][wr] = w1.z; Ws[wk + 7][wr] = w1.w;
    __syncthreads();
#pragma unroll
    for (int k = 0; k < 32; ++k) {
      const float a  = As[ty][k];
      const float4 w = *(const float4*)&Ws[k][tx << 2];
      acc0 += a * w.x; acc1 += a * w.y; acc2 += a * w.z; acc3 += a * w.w;
    }
    __syncthreads();
  }
  const float4 bb = *(const float4*)(bcat + bn + (tx << 2));
  const int jc = (bn >> 2) + tx;
  const int m  = bm + ty;
  const float ig = fsigm(acc0 + bb.x);
  const float fg = fsigm(acc1 + bb.y);
  const float gg = ftanh(acc2 + bb.z);
  const float og = fsigm(acc3 + bb.w);
  const float c  = fg * cin[(m << 8) + jc] + ig * gg;
  const float h  = og * ftanh(c);
  cnew[(m << 8) + jc] = c;
  hnew[(m << 8) + jc] = h;
}

// ---------------------------------------------------------------------------
// Fused per-step attention, TWO batch rows per block (b0 = 2*blk, b0+1).
// Matvec weight float4s are read ONCE and applied to both rows -> per-step
// L2 weight traffic halves (256 MB -> 128 MB). Per-row arithmetic (matvec
// k-order, strided lidx partition, online-softmax, scores, argmax) is
// bitwise-identical to the round-9-verified kernel.
// grid 256 x 512 threads.
// ---------------------------------------------------------------------------
__global__ __launch_bounds__(512) void step_attn_k(
    const float* __restrict__ h, const float* __restrict__ e2g,
    const float* __restrict__ e2p, const float* __restrict__ Wq1T4,
    const float* __restrict__ Wqp4, const float* __restrict__ qcour,
    const float* __restrict__ bqp, const float* __restrict__ vg,
    const float* __restrict__ vp, unsigned long long* __restrict__ mask,
    int* __restrict__ idxb, const float* __restrict__ emb,
    float* __restrict__ out_logp, float* __restrict__ out_sel,
    float* __restrict__ xb, int t)
{
  const int blk = blockIdx.x, tid = threadIdx.x;
  const int b0 = blk << 1;
  __shared__ __align__(16) float hs[2][256], qgs[2][256], qps[2][256], gls[2][256];
  __shared__ __align__(16) float vgs[256], vps[256];
  __shared__ __align__(16) float glp[2][8][256];
  __shared__ __align__(16) float part[1024];
  __shared__ float us[2][64], mxs[2][8], zws[2][8];
  __shared__ int lidx[2][64];
  __shared__ int lcnt[2];
  __shared__ int bsel[2];
  if (tid < 256) {
    hs[0][tid] = h[(b0 << 8) + tid];
    vgs[tid] = vg[tid];
    vps[tid] = vp[tid];
  } else {
    hs[1][tid - 256] = h[((b0 + 1) << 8) + (tid - 256)];
  }
  if (tid >= 384) {                       // prefill us with NEGV (masked l)
    const int r = (tid - 384) >> 6;
    us[r][tid & 63] = NEGV;
  }
  if (tid < 2) {                          // mask update + compact list, per row
    const int b = b0 + tid;
    unsigned long long m = mask[b];
    if (t > 0) {
      int s = idxb[b]; if (s < 0) s = 0;
      m |= (1ULL << s);
      if (m == ~0ULL) m &= ~(1ULL << 63);
      mask[b] = m;
    }
    int c = 0;
    for (int l = 0; l < 64; ++l)
      if (!((m >> l) & 1ULL)) lidx[tid][c++] = l;
    lcnt[tid] = c;                        // >= 1 (full mask prevented)
  }
  __syncthreads();
  const int cnt0 = lcnt[0], cnt1 = lcnt[1];
  const int w = tid >> 6, lane = tid & 63;
  const int o = tid & 255, kh = tid >> 8;

  // phase 0: qg for BOTH rows; each weight float4 read once (split-k x2)
  {
    float acc0 = (kh == 0) ? qcour[(b0 << 8) + o] : 0.f;
    float acc1 = (kh == 0) ? qcour[((b0 + 1) << 8) + o] : 0.f;
    const float4* wp = (const float4*)Wq1T4 + o;
    const int kc0 = kh << 5;
#pragma unroll 8
    for (int kc = kc0; kc < kc0 + 32; ++kc) {
      const float4 wv  = wp[kc << 8];
      const float4 h40 = *(const float4*)&hs[0][kc << 2];
      const float4 h41 = *(const float4*)&hs[1][kc << 2];
      acc0 += wv.x * h40.x + wv.y * h40.y + wv.z * h40.z + wv.w * h40.w;
      acc1 += wv.x * h41.x + wv.y * h41.y + wv.z * h41.z + wv.w * h41.w;
    }
    part[tid] = acc0; part[512 + tid] = acc1;
  }
  __syncthreads();
  if (tid < 256) qgs[0][tid] = part[tid] + part[tid + 256];
  else { const int o2 = tid - 256; qgs[1][o2] = part[512 + o2] + part[768 + o2]; }
  __syncthreads();

  // scores_g over compacted unmasked l's (strided across 8 waves), per row,
  // with online-softmax accumulation of gl. Row arithmetic == round 9.
  {
    const float4 v4 = *(const float4*)&vgs[lane << 2];
#pragma unroll
    for (int r = 0; r < 2; ++r) {
      const int cnt = r ? cnt1 : cnt0;
      const float4 q4 = *(const float4*)&qgs[r][lane << 2];
      const float* ebase = e2g + ((size_t)(b0 + r) << 8) + (lane << 2);
      float g0 = 0.f, g1 = 0.f, g2 = 0.f, g3 = 0.f;
      float mxw = -1e30f, zw = 0.f;
      for (int i = w; i < cnt; i += 8) {
        const int l = lidx[r][i];
        const float4 e4 = *(const float4*)(ebase + ((size_t)l << 17));
        float s = v4.x * ftanh(q4.x + e4.x) + v4.y * ftanh(q4.y + e4.y)
                + v4.z * ftanh(q4.z + e4.z) + v4.w * ftanh(q4.w + e4.w);
#pragma unroll
        for (int off = 32; off; off >>= 1) s += __shfl_xor(s, off, 64);
        const float nm   = fmaxf(mxw, s);
        const float corr = __expf(mxw - nm);   // 0 on first hit (mxw=-1e30)
        const float wl   = __expf(s - nm);
        zw = zw * corr + wl;
        g0 = g0 * corr + wl * e4.x; g1 = g1 * corr + wl * e4.y;
        g2 = g2 * corr + wl * e4.z; g3 = g3 * corr + wl * e4.w;
        mxw = nm;
      }
      glp[r][w][(lane << 2) + 0] = g0; glp[r][w][(lane << 2) + 1] = g1;
      glp[r][w][(lane << 2) + 2] = g2; glp[r][w][(lane << 2) + 3] = g3;
      if (lane == 0) { mxs[r][w] = mxw; zws[r][w] = zw; }
    }
  }
  __syncthreads();
  {
    const int r = tid >> 8, oo = tid & 255;
    float MX = mxs[r][0];
#pragma unroll
    for (int ww = 1; ww < 8; ++ww) MX = fmaxf(MX, mxs[r][ww]);
    float Z = 0.f, go = 0.f;
#pragma unroll
    for (int ww = 0; ww < 8; ++ww) {
      const float sc = __expf(mxs[r][ww] - MX);   // 0 for item-less waves
      Z  += sc * zws[r][ww];
      go += sc * glp[r][ww][oo];
    }
    gls[r][oo] = go / Z;
  }
  __syncthreads();

  // qp for BOTH rows; weights read once (split-k x2)
  {
    float acc0 = (kh == 0) ? bqp[o] : 0.f;
    float acc1 = (kh == 0) ? bqp[o] : 0.f;
    const float4* wp = (const float4*)Wqp4 + o;
    const int kc0 = kh << 5;
#pragma unroll 8
    for (int kc = kc0; kc < kc0 + 32; ++kc) {
      const float4 wv  = wp[kc << 8];
      const float4 g40 = *(const float4*)&gls[0][kc << 2];
      const float4 g41 = *(const float4*)&gls[1][kc << 2];
      acc0 += wv.x * g40.x + wv.y * g40.y + wv.z * g40.z + wv.w * g40.w;
      acc1 += wv.x * g41.x + wv.y * g41.y + wv.z * g41.z + wv.w * g41.w;
    }
    part[tid] = acc0; part[512 + tid] = acc1;
  }
  __syncthreads();
  if (tid < 256) qps[0][tid] = part[tid] + part[tid + 256];
  else { const int o2 = tid - 256; qps[1][o2] = part[512 + o2] + part[768 + o2]; }
  __syncthreads();

  // scores_p over compacted l's (strided), 10*tanh -> us[r]
  {
    const float4 v4 = *(const float4*)&vps[lane << 2];
#pragma unroll
    for (int r = 0; r < 2; ++r) {
      const int cnt = r ? cnt1 : cnt0;
      const float4 q4 = *(const float4*)&qps[r][lane << 2];
      const float* ebase = e2p + ((size_t)(b0 + r) << 8) + (lane << 2);
      for (int i = w; i < cnt; i += 8) {
        const int l = lidx[r][i];
        const float4 e4 = *(const float4*)(ebase + ((size_t)l << 17));
        float s = v4.x * ftanh(q4.x + e4.x) + v4.y * ftanh(q4.y + e4.y)
                + v4.z * ftanh(q4.z + e4.z) + v4.w * ftanh(q4.w + e4.w);
#pragma unroll
        for (int off = 32; off; off >>= 1) s += __shfl_xor(s, off, 64);
        if (lane == 0) us[r][l] = 10.0f * ftanh(s);
      }
    }
  }
  __syncthreads();
  if (tid < 128) {                        // wave 0 -> row 0, wave 1 -> row 1
    const int r = tid >> 6, l = tid & 63;
    const int b = b0 + r;
    const float xv = us[r][l];
    float mx = xv;
#pragma unroll
    for (int off = 32; off; off >>= 1) mx = fmaxf(mx, __shfl_xor(mx, off, 64));
    const float sh = xv - mx;
    const float ev = __expf(sh);
    float sum = ev;
#pragma unroll
    for (int off = 32; off; off >>= 1) sum += __shfl_xor(sum, off, 64);
    const float lp = sh - __logf(sum);
    out_logp[((size_t)b << 12) + (t << 6) + l] = lp;
    float bv = lp; int bi = l;
#pragma unroll
    for (int off = 32; off; off >>= 1) {
      const float ov = __shfl_xor(bv, off, 64);
      const int   oi = __shfl_xor(bi, off, 64);
      if (ov > bv || (ov == bv && oi < bi)) { bv = ov; bi = oi; }
    }
    if (l == 0) { idxb[b] = bi; out_sel[(b << 6) + t] = (float)bi; bsel[r] = bi; }
  }
  __syncthreads();
  {
    const int r = tid >> 8, col = tid & 255;
    xb[((b0 + r) << 8) + col] =
        emb[(((size_t)(bsel[r] << 9) + (b0 + r)) << 8) + col];
  }
}

// ---------------------------------------------------------------------------
// setup kernels
// ---------------------------------------------------------------------------
__global__ __launch_bounds__(256) void init_k(
    const float* __restrict__ dec, const float* __restrict__ h0,
    const float* __restrict__ c0, float* __restrict__ xb,
    float* __restrict__ hb, float* __restrict__ cb,
    unsigned long long* __restrict__ mask, int* __restrict__ idxb)
{
  const int i = blockIdx.x * 256 + threadIdx.x;
  xb[i] = dec[i]; hb[i] = h0[i]; cb[i] = c0[i];
  if (i < 512) { mask[i] = 0ULL; idxb[i] = -1; }
}

// Wcat[n][k], n=4*j+p interleaved (p in {i,f,g,o}), k = [x-part | h-part]
__global__ __launch_bounds__(256) void prep_wcat_k(
    const float* __restrict__ Wih, const float* __restrict__ Whh,
    const float* __restrict__ bih, const float* __restrict__ bhh,
    float* __restrict__ Wcat, float* __restrict__ bcat)
{
  const int id = blockIdx.x * 256 + threadIdx.x;
  const int n = id >> 9, k = id & 511;
  const int r = ((n & 3) << 8) + (n >> 2);
  Wcat[id] = (k < 256) ? Wih[(r << 8) + k] : Whh[(r << 8) + (k - 256)];
  if (id < 1024) {
    const int rr = ((id & 3) << 8) + (id >> 2);
    bcat[id] = bih[rr] + bhh[rr];
  }
}

// Wfused = Wq_g @ Wm (256x320), bfused = Wq_g @ bm + bq_g
__global__ __launch_bounds__(256) void prep_wfused_k(
    const float* __restrict__ Wqg, const float* __restrict__ Wm,
    const float* __restrict__ bm, const float* __restrict__ bqg,
    float* __restrict__ Wf, float* __restrict__ bf)
{
  const int id = blockIdx.x * 256 + threadIdx.x;  // 81920
  const int o = id / 320, j = id % 320;
  float acc = 0.f;
  for (int tt = 0; tt < 256; ++tt) acc += Wqg[(o << 8) + tt] * Wm[tt * 320 + j];
  Wf[id] = acc;
  if (id < 256) {
    float a2 = 0.f;
    for (int tt = 0; tt < 256; ++tt) a2 += Wqg[(id << 8) + tt] * bm[tt];
    bf[id] = a2 + bqg[id];
  }
}

// Wq1T4: packed transpose of Wfused[:, :256] for coalesced float4 matvec.
__global__ __launch_bounds__(256) void prep_wq1t4_k(
    const float* __restrict__ Wf, float* __restrict__ Wq1T4)
{
  const int id = blockIdx.x * 256 + threadIdx.x;  // 65536
  const int k = id >> 8, o = id & 255;
  Wq1T4[((k >> 2) << 10) + (o << 2) + (k & 3)] = Wf[o * 320 + k];
}

// Wqp4: packed transpose of raw Wqp for coalesced float4 matvec.
__global__ __launch_bounds__(256) void prep_wqp4_k(
    const float* __restrict__ Wqp, float* __restrict__ Wqp4)
{
  const int id = blockIdx.x * 256 + threadIdx.x;  // 65536
  const int k = id >> 8, o = id & 255;
  Wqp4[((k >> 2) << 10) + (o << 2) + (k & 3)] = Wqp[(o << 8) + k];
}

// qcour[b,o] = bfused[o] + sum_{k<64} Wfused[o][256+k] * cour[b][k]
__global__ __launch_bounds__(256) void prep_qcour_k(
    const float* __restrict__ Wf, const float* __restrict__ bf,
    const float* __restrict__ cour, float* __restrict__ qcour)
{
  const int b = blockIdx.x, o = threadIdx.x;
  __shared__ float cs[64];
  if (o < 64) cs[o] = cour[(b << 6) + o];
  __syncthreads();
  float acc = bf[o];
#pragma unroll 8
  for (int k = 0; k < 64; ++k) acc += Wf[o * 320 + 256 + k] * cs[k];
  qcour[(b << 8) + o] = acc;
}

// W2 rows 0..255 = Wrg, rows 256..511 = Wrp; b2 = {brg | brp}
__global__ __launch_bounds__(256) void prep_w2copy_k(
    const float* __restrict__ Wrg, const float* __restrict__ Wrp,
    const float* __restrict__ brg, const float* __restrict__ brp,
    float* __restrict__ W2, float* __restrict__ b2)
{
  const int id = blockIdx.x * 256 + threadIdx.x;   // 131072
  W2[id] = (id < 65536) ? Wrg[id] : Wrp[id - 65536];
  if (id < 256) b2[id] = brg[id];
  else if (id < 512) b2[id] = brp[id - 256];
}

// ---------------------------------------------------------------------------
extern "C" void kernel_launch(void* const* d_in, const int* in_sizes, int n_in,
                              void* d_out, int out_size, void* d_ws, size_t ws_size,
                              hipStream_t stream)
{
  const float* dec   = (const float*)d_in[0];
  const float* emb   = (const float*)d_in[1];
  const float* h0    = (const float*)d_in[2];
  const float* c0    = (const float*)d_in[3];
  const float* ctxin = (const float*)d_in[4];
  const float* cour  = (const float*)d_in[5];
  const float* Wih   = (const float*)d_in[7];
  const float* Whh   = (const float*)d_in[8];
  const float* bih   = (const float*)d_in[9];
  const float* bhh   = (const float*)d_in[10];
  const float* Wm    = (const float*)d_in[11];
  const float* bm    = (const float*)d_in[12];
  const float* Wqp   = (const float*)d_in[13];
  const float* bqp   = (const float*)d_in[14];
  const float* Wrp   = (const float*)d_in[15];
  const float* brp   = (const float*)d_in[16];
  const float* vp    = (const float*)d_in[17];
  const float* Wqg   = (const float*)d_in[18];
  const float* bqg   = (const float*)d_in[19];
  const float* Wrg   = (const float*)d_in[20];
  const float* brg   = (const float*)d_in[21];
  const float* vg    = (const float*)d_in[22];

  float* ws = (float*)d_ws;
  float* e2g    = ws + 0;         // 8388608
  float* e2p    = ws + 8388608;   // 8388608
  float* W2     = ws + 16777216;  // 131072
  float* b2     = ws + 16908288;  // 512
  float* Wcat   = ws + 16908800;  // 524288
  float* bcat   = ws + 17433088;  // 1024
  float* Wfused = ws + 17434112;  // 81920
  float* bfused = ws + 17516032;  // 256
  float* Wq1T4  = ws + 17516288;  // 65536
  float* Wqp4   = ws + 17581824;  // 65536
  float* qcour  = ws + 17647360;  // 131072
  float* hb0    = ws + 17778432;  // 131072
  float* hb1    = ws + 17909504;  // 131072
  float* cb0    = ws + 18040576;  // 131072
  float* cb1    = ws + 18171648;  // 131072
  float* xb     = ws + 18302720;  // 131072
  unsigned long long* maskb = (unsigned long long*)(ws + 18433792); // 512 u64
  int* idxb     = (int*)(ws + 18434816);                            // 512

  float* out_logp = (float*)d_out;            // [B][64][64]
  float* out_sel  = (float*)d_out + 2097152;  // [B][64]

  // ---- setup ----
  init_k<<<512, 256, 0, stream>>>(dec, h0, c0, xb, hb0, cb0, maskb, idxb);
  prep_wcat_k<<<2048, 256, 0, stream>>>(Wih, Whh, bih, bhh, Wcat, bcat);
  prep_wfused_k<<<320, 256, 0, stream>>>(Wqg, Wm, bm, bqg, Wfused, bfused);
  prep_wq1t4_k<<<256, 256, 0, stream>>>(Wfused, Wq1T4);
  prep_wqp4_k<<<256, 256, 0, stream>>>(Wqp, Wqp4);
  prep_qcour_k<<<512, 256, 0, stream>>>(Wfused, bfused, cour, qcour);
  prep_w2copy_k<<<512, 256, 0, stream>>>(Wrg, Wrp, brg, brp, W2, b2);
  gemm2_k<<<dim3(256, 4), 256, 0, stream>>>(ctxin, W2, b2, e2g, e2p);

  // ---- 64 sequential steps, 2 kernels each ----
  for (int t = 0; t < 64; ++t) {
    float* hcur = (t & 1) ? hb1 : hb0;
    float* hnew = (t & 1) ? hb0 : hb1;
    float* ccur = (t & 1) ? cb1 : cb0;
    float* cnew = (t & 1) ? cb0 : cb1;
    gates_lstm_k<<<dim3(16, 32), 256, 0, stream>>>(xb, hcur, Wcat, bcat,
                                                   ccur, cnew, hnew);
    step_attn_k<<<256, 512, 0, stream>>>(hnew, e2g, e2p, Wq1T4, Wqp4, qcour,
                                         bqp, vg, vp, maskb, idxb, emb,
                                         out_logp, out_sel, xb, t);
  }
}

// Round 11
// 2943.658 us; speedup vs baseline: 1.0508x; 1.0508x over previous
//
#include <hip/hip_runtime.h>
#include <cstdint>
#include <cstddef>

#define NEGV -1000000000.0f

// ---------- fast device math (fp32, argmax-safe) ----------
__device__ __forceinline__ float fsigm(float x) {
  return 1.0f / (1.0f + __expf(-x));
}
__device__ __forceinline__ float ftanh(float x) {
  x = fminf(x, 30.0f);
  const float e = __expf(2.0f * x);
  return (e - 1.0f) / (e + 1.0f);
}

// ---------------------------------------------------------------------------
// Fused setup GEMM: both context projections in one pass (shared A reads).
// grid(256,4): blockIdx.x = M-tile (fast dim) so the 4 N-tiles sharing one
// A-panel land on the same XCD -> L2 hit. Register double-buffered K-loop.
// (verified rounds 3/4/8/9/10: ~115 us, FETCH 58 MB)
// ---------------------------------------------------------------------------
__global__ __launch_bounds__(256, 2) void gemm2_k(
    const float* __restrict__ A0, const float* __restrict__ W2,
    const float* __restrict__ b2, float* __restrict__ Cg,
    float* __restrict__ Cp)
{
  __shared__ float As[16][136];     // [k][m]
  __shared__ float Ws[2][16][72];   // [s][k][n]
  const int bm = blockIdx.x << 7;   // fast dim
  const int bn = blockIdx.y << 6;
  const int t  = threadIdx.x;
  const int ty = t >> 4, tx = t & 15;
  const int ar = t >> 1, ac = (t & 1) << 3;   // A staging: 2 float4
  const int wr = t >> 2, wc = (t & 3) << 2;   // W staging: 1 float4 per s
  const float* arow = A0 + (size_t)(bm + ar) * 256 + ac;
  const float* w0row = W2 + (size_t)(bn + wr) * 256 + wc;
  const float* w1row = W2 + (size_t)(256 + bn + wr) * 256 + wc;
  float acc[2][8][4] = {};
  float4 a0 = *(const float4*)(arow + 0);
  float4 a1 = *(const float4*)(arow + 4);
  float4 wv0 = *(const float4*)(w0row + 0);
  float4 wv1 = *(const float4*)(w1row + 0);
  for (int k0 = 0; k0 < 256; k0 += 16) {
    As[ac + 0][ar] = a0.x; As[ac + 1][ar] = a0.y; As[ac + 2][ar] = a0.z; As[ac + 3][ar] = a0.w;
    As[ac + 4][ar] = a1.x; As[ac + 5][ar] = a1.y; As[ac + 6][ar] = a1.z; As[ac + 7][ar] = a1.w;
    Ws[0][wc + 0][wr] = wv0.x; Ws[0][wc + 1][wr] = wv0.y;
    Ws[0][wc + 2][wr] = wv0.z; Ws[0][wc + 3][wr] = wv0.w;
    Ws[1][wc + 0][wr] = wv1.x; Ws[1][wc + 1][wr] = wv1.y;
    Ws[1][wc + 2][wr] = wv1.z; Ws[1][wc + 3][wr] = wv1.w;
    __syncthreads();
    if (k0 < 240) {
      a0  = *(const float4*)(arow + k0 + 16);
      a1  = *(const float4*)(arow + k0 + 20);
      wv0 = *(const float4*)(w0row + k0 + 16);
      wv1 = *(const float4*)(w1row + k0 + 16);
    }
#pragma unroll
    for (int k = 0; k < 16; ++k) {
      const float4 a0v = *(const float4*)&As[k][ty << 3];
      const float4 a1v = *(const float4*)&As[k][(ty << 3) + 4];
      const float am[8] = {a0v.x, a0v.y, a0v.z, a0v.w, a1v.x, a1v.y, a1v.z, a1v.w};
#pragma unroll
      for (int s = 0; s < 2; ++s) {
        const float4 wv = *(const float4*)&Ws[s][k][tx << 2];
#pragma unroll
        for (int i = 0; i < 8; ++i) {
          acc[s][i][0] += am[i] * wv.x;
          acc[s][i][1] += am[i] * wv.y;
          acc[s][i][2] += am[i] * wv.z;
          acc[s][i][3] += am[i] * wv.w;
        }
      }
    }
    __syncthreads();
  }
  const int cn = bn + (tx << 2);
  const float4 bg = *(const float4*)(b2 + cn);
  const float4 bp = *(const float4*)(b2 + 256 + cn);
#pragma unroll
  for (int i = 0; i < 8; ++i) {
    const size_t row = ((size_t)(bm + (ty << 3) + i)) << 8;
    float4 o;
    o.x = acc[0][i][0] + bg.x; o.y = acc[0][i][1] + bg.y;
    o.z = acc[0][i][2] + bg.z; o.w = acc[0][i][3] + bg.w;
    *(float4*)(Cg + row + cn) = o;
    o.x = acc[1][i][0] + bp.x; o.y = acc[1][i][1] + bp.y;
    o.z = acc[1][i][2] + bp.z; o.w = acc[1][i][3] + bp.w;
    *(float4*)(Cp + row + cn) = o;
  }
}

// ---------------------------------------------------------------------------
// gates GEMM (M=512, N=1024 interleaved i,f,g,o per unit, K=512 = [x|h])
// + fused LSTM epilogue. BM=16, BN=64, BK=32 -> 512 blocks (2/CU).
// NEW: reads x directly from emb via idxb (t>0) or dec (t==0) -- removes the
// xb materialization round-trip. Same values, same coalescing (16 threads
// per row read 128B contiguous), arithmetic unchanged.
// ---------------------------------------------------------------------------
__global__ __launch_bounds__(256) void gates_lstm_k(
    const float* __restrict__ dec, const float* __restrict__ emb,
    const int* __restrict__ idxb, const float* __restrict__ hin,
    const float* __restrict__ Wcat, const float* __restrict__ bcat,
    const float* __restrict__ cin, float* __restrict__ cnew,
    float* __restrict__ hnew, int t)
{
  __shared__ __align__(16) float As[16][36];   // [m][k]
  __shared__ __align__(16) float Ws[32][68];   // [k][n]
  const int bn = blockIdx.x << 6;
  const int bm = blockIdx.y << 4;
  const int tt = threadIdx.x;
  const int ty = tt >> 4, tx = tt & 15;
  const int ar = tt >> 4, ak = (tt & 15) << 1;   // A staging: one float2
  const int wr = tt >> 2, wk = (tt & 3) << 3;    // W staging: two float4
  const float* wrow = Wcat + ((size_t)(bn + wr) << 9);
  const int arow = bm + ar;
  const float* xrow;
  if (t == 0) xrow = dec + ((size_t)arow << 8);
  else        xrow = emb + (((size_t)(idxb[arow] << 9) + (size_t)arow) << 8);
  float acc0 = 0.f, acc1 = 0.f, acc2 = 0.f, acc3 = 0.f;
  for (int k0 = 0; k0 < 512; k0 += 32) {
    const int kk = k0 + ak;
    float2 av;
    if (kk < 256) av = *(const float2*)(xrow + kk);
    else          av = *(const float2*)(hin + ((size_t)arow << 8) + (kk - 256));
    const float4 w0 = *(const float4*)(wrow + k0 + wk);
    const float4 w1 = *(const float4*)(wrow + k0 + wk + 4);
    *(float2*)&As[ar][ak] = av;
    Ws[wk + 0][wr] = w0.x; Ws[wk + 1][wr] = w0.y; Ws[wk + 2][wr] = w0.z; Ws[wk + 3][wr] = w0.w;
    Ws[wk + 4][wr] = w1.x; Ws[wk + 5][wr] = w1.y; Ws[wk + 6][wr] = w1.z; Ws[wk + 7][wr] = w1.w;
    __syncthreads();
#pragma unroll
    for (int k = 0; k < 32; ++k) {
      const float a  = As[ty][k];
      const float4 w = *(const float4*)&Ws[k][tx << 2];
      acc0 += a * w.x; acc1 += a * w.y; acc2 += a * w.z; acc3 += a * w.w;
    }
    __syncthreads();
  }
  const float4 bb = *(const float4*)(bcat + bn + (tx << 2));
  const int jc = (bn >> 2) + tx;
  const int m  = bm + ty;
  const float ig = fsigm(acc0 + bb.x);
  const float fg = fsigm(acc1 + bb.y);
  const float gg = ftanh(acc2 + bb.z);
  const float og = fsigm(acc3 + bb.w);
  const float c  = fg * cin[(m << 8) + jc] + ig * gg;
  const float h  = og * ftanh(c);
  cnew[(m << 8) + jc] = c;
  hnew[(m << 8) + jc] = h;
}

// ---------------------------------------------------------------------------
// Fused per-step attention (round-9-verified arithmetic: compacted strided
// mask-skip). One block of 512 threads per batch row b (2 blocks/CU).
// NEW: no xb gather tail -- gates reads emb directly next step.
// ---------------------------------------------------------------------------
__global__ __launch_bounds__(512) void step_attn_k(
    const float* __restrict__ h, const float* __restrict__ e2g,
    const float* __restrict__ e2p, const float* __restrict__ Wq1T4,
    const float* __restrict__ Wqp4, const float* __restrict__ qcour,
    const float* __restrict__ bqp, const float* __restrict__ vg,
    const float* __restrict__ vp, unsigned long long* __restrict__ mask,
    int* __restrict__ idxb, float* __restrict__ out_logp,
    float* __restrict__ out_sel, int t)
{
  const int b = blockIdx.x, tid = threadIdx.x;
  __shared__ __align__(16) float hs[256], qgs[256], qps[256], gls[256];
  __shared__ __align__(16) float vgs[256], vps[256];
  __shared__ __align__(16) float glp[8][256];
  __shared__ __align__(16) float part[512];
  __shared__ float us[64], mxs[8], zws[8];
  __shared__ int lidx[64];
  __shared__ int lcnt;
  if (tid < 256) {
    hs[tid]  = h[(b << 8) + tid];
    vgs[tid] = vg[tid];
    vps[tid] = vp[tid];
  }
  if (tid >= 256 && tid < 320) us[tid - 256] = NEGV;   // masked l -> NEGV
  if (tid == 0) {
    unsigned long long m = mask[b];
    if (t > 0) {
      int s = idxb[b]; if (s < 0) s = 0;
      m |= (1ULL << s);
      if (m == ~0ULL) m &= ~(1ULL << 63);
      mask[b] = m;
    }
    int c = 0;
    for (int l = 0; l < 64; ++l)
      if (!((m >> l) & 1ULL)) lidx[c++] = l;
    lcnt = c;                                  // >= 1 (full mask prevented)
  }
  __syncthreads();
  const int cnt = lcnt;
  const int w = tid >> 6, lane = tid & 63;
  const int o = tid & 255, kh = tid >> 8;

  // phase 0: qg[o] = qcour[b,o] + sum_k Wq1[o][k] * h[b,k]  (split-k x2)
  {
    float acc = (kh == 0) ? qcour[(b << 8) + o] : 0.f;
    const float4* wp = (const float4*)Wq1T4 + o;
    const int kc0 = kh << 5;
#pragma unroll 8
    for (int kc = kc0; kc < kc0 + 32; ++kc) {
      const float4 wv = wp[kc << 8];
      const float4 h4 = *(const float4*)&hs[kc << 2];
      acc += wv.x * h4.x + wv.y * h4.y + wv.z * h4.z + wv.w * h4.w;
    }
    part[tid] = acc;
  }
  __syncthreads();
  if (tid < 256) qgs[tid] = part[tid] + part[tid + 256];
  __syncthreads();

  // scores_g over compacted unmasked l's (strided across waves) +
  // online-softmax accumulation of gl.
  {
    const float4 q4 = *(const float4*)&qgs[lane << 2];
    const float4 v4 = *(const float4*)&vgs[lane << 2];
    const float* ebase = e2g + ((size_t)b << 8) + (lane << 2);
    float g0 = 0.f, g1 = 0.f, g2 = 0.f, g3 = 0.f;
    float mxw = -1e30f, zw = 0.f;
    for (int i = w; i < cnt; i += 8) {
      const int l = lidx[i];
      const float4 e4 = *(const float4*)(ebase + ((size_t)l << 17));
      float s = v4.x * ftanh(q4.x + e4.x) + v4.y * ftanh(q4.y + e4.y)
              + v4.z * ftanh(q4.z + e4.z) + v4.w * ftanh(q4.w + e4.w);
#pragma unroll
      for (int off = 32; off; off >>= 1) s += __shfl_xor(s, off, 64);
      const float nm   = fmaxf(mxw, s);
      const float corr = __expf(mxw - nm);   // 0 on first hit (mxw=-1e30)
      const float wl   = __expf(s - nm);
      zw = zw * corr + wl;
      g0 = g0 * corr + wl * e4.x; g1 = g1 * corr + wl * e4.y;
      g2 = g2 * corr + wl * e4.z; g3 = g3 * corr + wl * e4.w;
      mxw = nm;
    }
    glp[w][(lane << 2) + 0] = g0; glp[w][(lane << 2) + 1] = g1;
    glp[w][(lane << 2) + 2] = g2; glp[w][(lane << 2) + 3] = g3;
    if (lane == 0) { mxs[w] = mxw; zws[w] = zw; }
  }
  __syncthreads();
  if (tid < 256) {
    float MX = mxs[0];
#pragma unroll
    for (int ww = 1; ww < 8; ++ww) MX = fmaxf(MX, mxs[ww]);
    float Z = 0.f, go = 0.f;
#pragma unroll
    for (int ww = 0; ww < 8; ++ww) {
      const float sc = __expf(mxs[ww] - MX);   // 0 for item-less waves
      Z  += sc * zws[ww];
      go += sc * glp[ww][tid];
    }
    gls[tid] = go / Z;
  }
  __syncthreads();

  // qp[o] = bqp[o] + sum_k Wqp[o][k] * gl[k]  (split-k x2)
  {
    float acc = (kh == 0) ? bqp[o] : 0.f;
    const float4* wp = (const float4*)Wqp4 + o;
    const int kc0 = kh << 5;
#pragma unroll 8
    for (int kc = kc0; kc < kc0 + 32; ++kc) {
      const float4 wv = wp[kc << 8];
      const float4 h4 = *(const float4*)&gls[kc << 2];
      acc += wv.x * h4.x + wv.y * h4.y + wv.z * h4.z + wv.w * h4.w;
    }
    part[tid] = acc;
  }
  __syncthreads();
  if (tid < 256) qps[tid] = part[tid] + part[tid + 256];
  __syncthreads();

  // scores_p over compacted unmasked l's (strided), 10*tanh -> us
  // (us pre-filled with NEGV for masked l's).
  {
    const float4 q4 = *(const float4*)&qps[lane << 2];
    const float4 v4 = *(const float4*)&vps[lane << 2];
    const float* ebase = e2p + ((size_t)b << 8) + (lane << 2);
    for (int i = w; i < cnt; i += 8) {
      const int l = lidx[i];
      const float4 e4 = *(const float4*)(ebase + ((size_t)l << 17));
      float s = v4.x * ftanh(q4.x + e4.x) + v4.y * ftanh(q4.y + e4.y)
              + v4.z * ftanh(q4.z + e4.z) + v4.w * ftanh(q4.w + e4.w);
#pragma unroll
      for (int off = 32; off; off >>= 1) s += __shfl_xor(s, off, 64);
      if (lane == 0) us[l] = 10.0f * ftanh(s);
    }
  }
  __syncthreads();
  if (tid < 64) {
    const float xv = us[tid];
    float mx = xv;
#pragma unroll
    for (int off = 32; off; off >>= 1) mx = fmaxf(mx, __shfl_xor(mx, off, 64));
    const float sh = xv - mx;
    const float ev = __expf(sh);
    float sum = ev;
#pragma unroll
    for (int off = 32; off; off >>= 1) sum += __shfl_xor(sum, off, 64);
    const float lp = sh - __logf(sum);
    out_logp[((size_t)b << 12) + (t << 6) + tid] = lp;
    float bv = lp; int bi = tid;
#pragma unroll
    for (int off = 32; off; off >>= 1) {
      const float ov = __shfl_xor(bv, off, 64);
      const int   oi = __shfl_xor(bi, off, 64);
      if (ov > bv || (ov == bv && oi < bi)) { bv = ov; bi = oi; }
    }
    if (tid == 0) { idxb[b] = bi; out_sel[(b << 6) + t] = (float)bi; }
  }
}

// ---------------------------------------------------------------------------
// setup kernels
// ---------------------------------------------------------------------------
__global__ __launch_bounds__(256) void init_k(
    const float* __restrict__ h0, const float* __restrict__ c0,
    float* __restrict__ hb, float* __restrict__ cb,
    unsigned long long* __restrict__ mask, int* __restrict__ idxb)
{
  const int i = blockIdx.x * 256 + threadIdx.x;
  hb[i] = h0[i]; cb[i] = c0[i];
  if (i < 512) { mask[i] = 0ULL; idxb[i] = -1; }
}

// Wcat[n][k], n=4*j+p interleaved (p in {i,f,g,o}), k = [x-part | h-part]
__global__ __launch_bounds__(256) void prep_wcat_k(
    const float* __restrict__ Wih, const float* __restrict__ Whh,
    const float* __restrict__ bih, const float* __restrict__ bhh,
    float* __restrict__ Wcat, float* __restrict__ bcat)
{
  const int id = blockIdx.x * 256 + threadIdx.x;
  const int n = id >> 9, k = id & 511;
  const int r = ((n & 3) << 8) + (n >> 2);
  Wcat[id] = (k < 256) ? Wih[(r << 8) + k] : Whh[(r << 8) + (k - 256)];
  if (id < 1024) {
    const int rr = ((id & 3) << 8) + (id >> 2);
    bcat[id] = bih[rr] + bhh[rr];
  }
}

// Wfused = Wq_g @ Wm (256x320), bfused = Wq_g @ bm + bq_g
__global__ __launch_bounds__(256) void prep_wfused_k(
    const float* __restrict__ Wqg, const float* __restrict__ Wm,
    const float* __restrict__ bm, const float* __restrict__ bqg,
    float* __restrict__ Wf, float* __restrict__ bf)
{
  const int id = blockIdx.x * 256 + threadIdx.x;  // 81920
  const int o = id / 320, j = id % 320;
  float acc = 0.f;
  for (int tt = 0; tt < 256; ++tt) acc += Wqg[(o << 8) + tt] * Wm[tt * 320 + j];
  Wf[id] = acc;
  if (id < 256) {
    float a2 = 0.f;
    for (int tt = 0; tt < 256; ++tt) a2 += Wqg[(id << 8) + tt] * bm[tt];
    bf[id] = a2 + bqg[id];
  }
}

// Wq1T4: packed transpose of Wfused[:, :256] for coalesced float4 matvec.
__global__ __launch_bounds__(256) void prep_wq1t4_k(
    const float* __restrict__ Wf, float* __restrict__ Wq1T4)
{
  const int id = blockIdx.x * 256 + threadIdx.x;  // 65536
  const int k = id >> 8, o = id & 255;
  Wq1T4[((k >> 2) << 10) + (o << 2) + (k & 3)] = Wf[o * 320 + k];
}

// Wqp4: packed transpose of raw Wqp for coalesced float4 matvec.
__global__ __launch_bounds__(256) void prep_wqp4_k(
    const float* __restrict__ Wqp, float* __restrict__ Wqp4)
{
  const int id = blockIdx.x * 256 + threadIdx.x;  // 65536
  const int k = id >> 8, o = id & 255;
  Wqp4[((k >> 2) << 10) + (o << 2) + (k & 3)] = Wqp[(o << 8) + k];
}

// qcour[b,o] = bfused[o] + sum_{k<64} Wfused[o][256+k] * cour[b][k]
__global__ __launch_bounds__(256) void prep_qcour_k(
    const float* __restrict__ Wf, const float* __restrict__ bf,
    const float* __restrict__ cour, float* __restrict__ qcour)
{
  const int b = blockIdx.x, o = threadIdx.x;
  __shared__ float cs[64];
  if (o < 64) cs[o] = cour[(b << 6) + o];
  __syncthreads();
  float acc = bf[o];
#pragma unroll 8
  for (int k = 0; k < 64; ++k) acc += Wf[o * 320 + 256 + k] * cs[k];
  qcour[(b << 8) + o] = acc;
}

// W2 rows 0..255 = Wrg, rows 256..511 = Wrp; b2 = {brg | brp}
__global__ __launch_bounds__(256) void prep_w2copy_k(
    const float* __restrict__ Wrg, const float* __restrict__ Wrp,
    const float* __restrict__ brg, const float* __restrict__ brp,
    float* __restrict__ W2, float* __restrict__ b2)
{
  const int id = blockIdx.x * 256 + threadIdx.x;   // 131072
  W2[id] = (id < 65536) ? Wrg[id] : Wrp[id - 65536];
  if (id < 256) b2[id] = brg[id];
  else if (id < 512) b2[id] = brp[id - 256];
}

// ---------------------------------------------------------------------------
extern "C" void kernel_launch(void* const* d_in, const int* in_sizes, int n_in,
                              void* d_out, int out_size, void* d_ws, size_t ws_size,
                              hipStream_t stream)
{
  const float* dec   = (const float*)d_in[0];
  const float* emb   = (const float*)d_in[1];
  const float* h0    = (const float*)d_in[2];
  const float* c0    = (const float*)d_in[3];
  const float* ctxin = (const float*)d_in[4];
  const float* cour  = (const float*)d_in[5];
  const float* Wih   = (const float*)d_in[7];
  const float* Whh   = (const float*)d_in[8];
  const float* bih   = (const float*)d_in[9];
  const float* bhh   = (const float*)d_in[10];
  const float* Wm    = (const float*)d_in[11];
  const float* bm    = (const float*)d_in[12];
  const float* Wqp   = (const float*)d_in[13];
  const float* bqp   = (const float*)d_in[14];
  const float* Wrp   = (const float*)d_in[15];
  const float* brp   = (const float*)d_in[16];
  const float* vp    = (const float*)d_in[17];
  const float* Wqg   = (const float*)d_in[18];
  const float* bqg   = (const float*)d_in[19];
  const float* Wrg   = (const float*)d_in[20];
  const float* brg   = (const float*)d_in[21];
  const float* vg    = (const float*)d_in[22];

  float* ws = (float*)d_ws;
  float* e2g    = ws + 0;         // 8388608
  float* e2p    = ws + 8388608;   // 8388608
  float* W2     = ws + 16777216;  // 131072
  float* b2     = ws + 16908288;  // 512
  float* Wcat   = ws + 16908800;  // 524288
  float* bcat   = ws + 17433088;  // 1024
  float* Wfused = ws + 17434112;  // 81920
  float* bfused = ws + 17516032;  // 256
  float* Wq1T4  = ws + 17516288;  // 65536
  float* Wqp4   = ws + 17581824;  // 65536
  float* qcour  = ws + 17647360;  // 131072
  float* hb0    = ws + 17778432;  // 131072
  float* hb1    = ws + 17909504;  // 131072
  float* cb0    = ws + 18040576;  // 131072
  float* cb1    = ws + 18171648;  // 131072
  unsigned long long* maskb = (unsigned long long*)(ws + 18302720); // 512 u64
  int* idxb     = (int*)(ws + 18303744);                            // 512

  float* out_logp = (float*)d_out;            // [B][64][64]
  float* out_sel  = (float*)d_out + 2097152;  // [B][64]

  // ---- setup ----
  init_k<<<512, 256, 0, stream>>>(h0, c0, hb0, cb0, maskb, idxb);
  prep_wcat_k<<<2048, 256, 0, stream>>>(Wih, Whh, bih, bhh, Wcat, bcat);
  prep_wfused_k<<<320, 256, 0, stream>>>(Wqg, Wm, bm, bqg, Wfused, bfused);
  prep_wq1t4_k<<<256, 256, 0, stream>>>(Wfused, Wq1T4);
  prep_wqp4_k<<<256, 256, 0, stream>>>(Wqp, Wqp4);
  prep_qcour_k<<<512, 256, 0, stream>>>(Wfused, bfused, cour, qcour);
  prep_w2copy_k<<<512, 256, 0, stream>>>(Wrg, Wrp, brg, brp, W2, b2);
  gemm2_k<<<dim3(256, 4), 256, 0, stream>>>(ctxin, W2, b2, e2g, e2p);

  // ---- 64 sequential steps, 2 kernels each ----
  for (int t = 0; t < 64; ++t) {
    float* hcur = (t & 1) ? hb1 : hb0;
    float* hnew = (t & 1) ? hb0 : hb1;
    float* ccur = (t & 1) ? cb1 : cb0;
    float* cnew = (t & 1) ? cb0 : cb1;
    gates_lstm_k<<<dim3(16, 32), 256, 0, stream>>>(dec, emb, idxb, hcur,
                                                   Wcat, bcat, ccur, cnew,
                                                   hnew, t);
    step_attn_k<<<512, 512, 0, stream>>>(hnew, e2g, e2p, Wq1T4, Wqp4, qcour,
                                         bqp, vg, vp, maskb, idxb,
                                         out_logp, out_sel, t);
  }
}

// Round 12
// 2786.075 us; speedup vs baseline: 1.1103x; 1.0566x over previous
//
#include <hip/hip_runtime.h>
#include <cstdint>
#include <cstddef>

#define NEGV -1000000000.0f

// ---------- fast device math (fp32, argmax-safe) ----------
__device__ __forceinline__ float fsigm(float x) {
  return 1.0f / (1.0f + __expf(-x));
}
__device__ __forceinline__ float ftanh(float x) {
  x = fminf(x, 30.0f);
  const float e = __expf(2.0f * x);
  return (e - 1.0f) / (e + 1.0f);
}

// ---------------------------------------------------------------------------
// Fused setup GEMM: both context projections in one pass (shared A reads).
// grid(256,4): blockIdx.x = M-tile (fast dim) so the 4 N-tiles sharing one
// A-panel land on the same XCD -> L2 hit. Register double-buffered K-loop.
// (verified rounds 3/4/8/9/10/11: ~115 us, FETCH 58 MB)
// ---------------------------------------------------------------------------
__global__ __launch_bounds__(256, 2) void gemm2_k(
    const float* __restrict__ A0, const float* __restrict__ W2,
    const float* __restrict__ b2, float* __restrict__ Cg,
    float* __restrict__ Cp)
{
  __shared__ float As[16][136];     // [k][m]
  __shared__ float Ws[2][16][72];   // [s][k][n]
  const int bm = blockIdx.x << 7;   // fast dim
  const int bn = blockIdx.y << 6;
  const int t  = threadIdx.x;
  const int ty = t >> 4, tx = t & 15;
  const int ar = t >> 1, ac = (t & 1) << 3;   // A staging: 2 float4
  const int wr = t >> 2, wc = (t & 3) << 2;   // W staging: 1 float4 per s
  const float* arow = A0 + (size_t)(bm + ar) * 256 + ac;
  const float* w0row = W2 + (size_t)(bn + wr) * 256 + wc;
  const float* w1row = W2 + (size_t)(256 + bn + wr) * 256 + wc;
  float acc[2][8][4] = {};
  float4 a0 = *(const float4*)(arow + 0);
  float4 a1 = *(const float4*)(arow + 4);
  float4 wv0 = *(const float4*)(w0row + 0);
  float4 wv1 = *(const float4*)(w1row + 0);
  for (int k0 = 0; k0 < 256; k0 += 16) {
    As[ac + 0][ar] = a0.x; As[ac + 1][ar] = a0.y; As[ac + 2][ar] = a0.z; As[ac + 3][ar] = a0.w;
    As[ac + 4][ar] = a1.x; As[ac + 5][ar] = a1.y; As[ac + 6][ar] = a1.z; As[ac + 7][ar] = a1.w;
    Ws[0][wc + 0][wr] = wv0.x; Ws[0][wc + 1][wr] = wv0.y;
    Ws[0][wc + 2][wr] = wv0.z; Ws[0][wc + 3][wr] = wv0.w;
    Ws[1][wc + 0][wr] = wv1.x; Ws[1][wc + 1][wr] = wv1.y;
    Ws[1][wc + 2][wr] = wv1.z; Ws[1][wc + 3][wr] = wv1.w;
    __syncthreads();
    if (k0 < 240) {
      a0  = *(const float4*)(arow + k0 + 16);
      a1  = *(const float4*)(arow + k0 + 20);
      wv0 = *(const float4*)(w0row + k0 + 16);
      wv1 = *(const float4*)(w1row + k0 + 16);
    }
#pragma unroll
    for (int k = 0; k < 16; ++k) {
      const float4 a0v = *(const float4*)&As[k][ty << 3];
      const float4 a1v = *(const float4*)&As[k][(ty << 3) + 4];
      const float am[8] = {a0v.x, a0v.y, a0v.z, a0v.w, a1v.x, a1v.y, a1v.z, a1v.w};
#pragma unroll
      for (int s = 0; s < 2; ++s) {
        const float4 wv = *(const float4*)&Ws[s][k][tx << 2];
#pragma unroll
        for (int i = 0; i < 8; ++i) {
          acc[s][i][0] += am[i] * wv.x;
          acc[s][i][1] += am[i] * wv.y;
          acc[s][i][2] += am[i] * wv.z;
          acc[s][i][3] += am[i] * wv.w;
        }
      }
    }
    __syncthreads();
  }
  const int cn = bn + (tx << 2);
  const float4 bg = *(const float4*)(b2 + cn);
  const float4 bp = *(const float4*)(b2 + 256 + cn);
#pragma unroll
  for (int i = 0; i < 8; ++i) {
    const size_t row = ((size_t)(bm + (ty << 3) + i)) << 8;
    float4 o;
    o.x = acc[0][i][0] + bg.x; o.y = acc[0][i][1] + bg.y;
    o.z = acc[0][i][2] + bg.z; o.w = acc[0][i][3] + bg.w;
    *(float4*)(Cg + row + cn) = o;
    o.x = acc[1][i][0] + bp.x; o.y = acc[1][i][1] + bp.y;
    o.z = acc[1][i][2] + bp.z; o.w = acc[1][i][3] + bp.w;
    *(float4*)(Cp + row + cn) = o;
  }
}

// ---------------------------------------------------------------------------
// gates GEMM (M=512, N=1024 interleaved i,f,g,o per unit, K=512 = [x|h])
// + fused LSTM epilogue. BM=16, BN=64, BK=32 -> 512 blocks (2/CU).
// (exact round-2/9-verified version)
// ---------------------------------------------------------------------------
__global__ __launch_bounds__(256) void gates_lstm_k(
    const float* __restrict__ x, const float* __restrict__ hin,
    const float* __restrict__ Wcat, const float* __restrict__ bcat,
    const float* __restrict__ cin, float* __restrict__ cnew,
    float* __restrict__ hnew)
{
  __shared__ __align__(16) float As[16][36];   // [m][k]
  __shared__ __align__(16) float Ws[32][68];   // [k][n]
  const int bn = blockIdx.x << 6;
  const int bm = blockIdx.y << 4;
  const int t  = threadIdx.x;
  const int ty = t >> 4, tx = t & 15;
  const int ar = t >> 4, ak = (t & 15) << 1;   // A staging: one float2
  const int wr = t >> 2, wk = (t & 3) << 3;    // W staging: two float4
  const float* wrow = Wcat + ((size_t)(bn + wr) << 9);
  const int arow = bm + ar;
  float acc0 = 0.f, acc1 = 0.f, acc2 = 0.f, acc3 = 0.f;
  for (int k0 = 0; k0 < 512; k0 += 32) {
    const int kk = k0 + ak;
    float2 av;
    if (kk < 256) av = *(const float2*)(x   + ((size_t)arow << 8) + kk);
    else          av = *(const float2*)(hin + ((size_t)arow << 8) + (kk - 256));
    const float4 w0 = *(const float4*)(wrow + k0 + wk);
    const float4 w1 = *(const float4*)(wrow + k0 + wk + 4);
    *(float2*)&As[ar][ak] = av;
    Ws[wk + 0][wr] = w0.x; Ws[wk + 1][wr] = w0.y; Ws[wk + 2][wr] = w0.z; Ws[wk + 3][wr] = w0.w;
    Ws[wk + 4][wr] = w1.x; Ws[wk + 5][wr] = w1.y; Ws[wk + 6][wr] = w1.z; Ws[wk + 7][wr] = w1.w;
    __syncthreads();
#pragma unroll
    for (int k = 0; k < 32; ++k) {
      const float a  = As[ty][k];
      const float4 w = *(const float4*)&Ws[k][tx << 2];
      acc0 += a * w.x; acc1 += a * w.y; acc2 += a * w.z; acc3 += a * w.w;
    }
    __syncthreads();
  }
  const float4 bb = *(const float4*)(bcat + bn + (tx << 2));
  const int jc = (bn >> 2) + tx;
  const int m  = bm + ty;
  const float ig = fsigm(acc0 + bb.x);
  const float fg = fsigm(acc1 + bb.y);
  const float gg = ftanh(acc2 + bb.z);
  const float og = fsigm(acc3 + bb.w);
  const float c  = fg * cin[(m << 8) + jc] + ig * gg;
  const float h  = og * ftanh(c);
  cnew[(m << 8) + jc] = c;
  hnew[(m << 8) + jc] = h;
}

// ---------------------------------------------------------------------------
// Fused per-step attention (round-9-verified arithmetic: compacted strided
// mask-skip). NEW: score loops unrolled x2 with ORDER-PRESERVING updates --
// two independent load/tanh/shuffle chains in flight per pass, online-softmax
// updates still applied in original (i, i+8) order -> bitwise-identical.
// One block of 512 threads per batch row b (2 blocks/CU).
// ---------------------------------------------------------------------------
__global__ __launch_bounds__(512) void step_attn_k(
    const float* __restrict__ h, const float* __restrict__ e2g,
    const float* __restrict__ e2p, const float* __restrict__ Wq1T4,
    const float* __restrict__ Wqp4, const float* __restrict__ qcour,
    const float* __restrict__ bqp, const float* __restrict__ vg,
    const float* __restrict__ vp, unsigned long long* __restrict__ mask,
    int* __restrict__ idxb, const float* __restrict__ emb,
    float* __restrict__ out_logp, float* __restrict__ out_sel,
    float* __restrict__ xb, int t)
{
  const int b = blockIdx.x, tid = threadIdx.x;
  __shared__ __align__(16) float hs[256], qgs[256], qps[256], gls[256];
  __shared__ __align__(16) float vgs[256], vps[256];
  __shared__ __align__(16) float glp[8][256];
  __shared__ __align__(16) float part[512];
  __shared__ float us[64], mxs[8], zws[8];
  __shared__ int lidx[64];
  __shared__ int lcnt;
  __shared__ int bsel;
  if (tid < 256) {
    hs[tid]  = h[(b << 8) + tid];
    vgs[tid] = vg[tid];
    vps[tid] = vp[tid];
  }
  if (tid >= 256 && tid < 320) us[tid - 256] = NEGV;   // masked l -> NEGV
  if (tid == 0) {
    unsigned long long m = mask[b];
    if (t > 0) {
      int s = idxb[b]; if (s < 0) s = 0;
      m |= (1ULL << s);
      if (m == ~0ULL) m &= ~(1ULL << 63);
      mask[b] = m;
    }
    int c = 0;
    for (int l = 0; l < 64; ++l)
      if (!((m >> l) & 1ULL)) lidx[c++] = l;
    lcnt = c;                                  // >= 1 (full mask prevented)
  }
  __syncthreads();
  const int cnt = lcnt;
  const int w = tid >> 6, lane = tid & 63;
  const int o = tid & 255, kh = tid >> 8;

  // phase 0: qg[o] = qcour[b,o] + sum_k Wq1[o][k] * h[b,k]  (split-k x2)
  {
    float acc = (kh == 0) ? qcour[(b << 8) + o] : 0.f;
    const float4* wp = (const float4*)Wq1T4 + o;
    const int kc0 = kh << 5;
#pragma unroll 8
    for (int kc = kc0; kc < kc0 + 32; ++kc) {
      const float4 wv = wp[kc << 8];
      const float4 h4 = *(const float4*)&hs[kc << 2];
      acc += wv.x * h4.x + wv.y * h4.y + wv.z * h4.z + wv.w * h4.w;
    }
    part[tid] = acc;
  }
  __syncthreads();
  if (tid < 256) qgs[tid] = part[tid] + part[tid + 256];
  __syncthreads();

  // scores_g over compacted unmasked l's (strided across waves), unroll x2,
  // online-softmax updates applied in original order (bitwise == round 9).
  {
    const float4 q4 = *(const float4*)&qgs[lane << 2];
    const float4 v4 = *(const float4*)&vgs[lane << 2];
    const float* ebase = e2g + ((size_t)b << 8) + (lane << 2);
    float g0 = 0.f, g1 = 0.f, g2 = 0.f, g3 = 0.f;
    float mxw = -1e30f, zw = 0.f;
    int i = w;
    for (; i + 8 < cnt; i += 16) {
      const int l0 = lidx[i], l1 = lidx[i + 8];
      const float4 e40 = *(const float4*)(ebase + ((size_t)l0 << 17));
      const float4 e41 = *(const float4*)(ebase + ((size_t)l1 << 17));
      float s0 = v4.x * ftanh(q4.x + e40.x) + v4.y * ftanh(q4.y + e40.y)
               + v4.z * ftanh(q4.z + e40.z) + v4.w * ftanh(q4.w + e40.w);
      float s1 = v4.x * ftanh(q4.x + e41.x) + v4.y * ftanh(q4.y + e41.y)
               + v4.z * ftanh(q4.z + e41.z) + v4.w * ftanh(q4.w + e41.w);
#pragma unroll
      for (int off = 32; off; off >>= 1) {
        s0 += __shfl_xor(s0, off, 64);
        s1 += __shfl_xor(s1, off, 64);
      }
      {
        const float nm   = fmaxf(mxw, s0);
        const float corr = __expf(mxw - nm);
        const float wl   = __expf(s0 - nm);
        zw = zw * corr + wl;
        g0 = g0 * corr + wl * e40.x; g1 = g1 * corr + wl * e40.y;
        g2 = g2 * corr + wl * e40.z; g3 = g3 * corr + wl * e40.w;
        mxw = nm;
      }
      {
        const float nm   = fmaxf(mxw, s1);
        const float corr = __expf(mxw - nm);
        const float wl   = __expf(s1 - nm);
        zw = zw * corr + wl;
        g0 = g0 * corr + wl * e41.x; g1 = g1 * corr + wl * e41.y;
        g2 = g2 * corr + wl * e41.z; g3 = g3 * corr + wl * e41.w;
        mxw = nm;
      }
    }
    if (i < cnt) {
      const int l = lidx[i];
      const float4 e4 = *(const float4*)(ebase + ((size_t)l << 17));
      float s = v4.x * ftanh(q4.x + e4.x) + v4.y * ftanh(q4.y + e4.y)
              + v4.z * ftanh(q4.z + e4.z) + v4.w * ftanh(q4.w + e4.w);
#pragma unroll
      for (int off = 32; off; off >>= 1) s += __shfl_xor(s, off, 64);
      const float nm   = fmaxf(mxw, s);
      const float corr = __expf(mxw - nm);
      const float wl   = __expf(s - nm);
      zw = zw * corr + wl;
      g0 = g0 * corr + wl * e4.x; g1 = g1 * corr + wl * e4.y;
      g2 = g2 * corr + wl * e4.z; g3 = g3 * corr + wl * e4.w;
      mxw = nm;
    }
    glp[w][(lane << 2) + 0] = g0; glp[w][(lane << 2) + 1] = g1;
    glp[w][(lane << 2) + 2] = g2; glp[w][(lane << 2) + 3] = g3;
    if (lane == 0) { mxs[w] = mxw; zws[w] = zw; }
  }
  __syncthreads();
  if (tid < 256) {
    float MX = mxs[0];
#pragma unroll
    for (int ww = 1; ww < 8; ++ww) MX = fmaxf(MX, mxs[ww]);
    float Z = 0.f, go = 0.f;
#pragma unroll
    for (int ww = 0; ww < 8; ++ww) {
      const float sc = __expf(mxs[ww] - MX);   // 0 for item-less waves
      Z  += sc * zws[ww];
      go += sc * glp[ww][tid];
    }
    gls[tid] = go / Z;
  }
  __syncthreads();

  // qp[o] = bqp[o] + sum_k Wqp[o][k] * gl[k]  (split-k x2)
  {
    float acc = (kh == 0) ? bqp[o] : 0.f;
    const float4* wp = (const float4*)Wqp4 + o;
    const int kc0 = kh << 5;
#pragma unroll 8
    for (int kc = kc0; kc < kc0 + 32; ++kc) {
      const float4 wv = wp[kc << 8];
      const float4 h4 = *(const float4*)&gls[kc << 2];
      acc += wv.x * h4.x + wv.y * h4.y + wv.z * h4.z + wv.w * h4.w;
    }
    part[tid] = acc;
  }
  __syncthreads();
  if (tid < 256) qps[tid] = part[tid] + part[tid + 256];
  __syncthreads();

  // scores_p over compacted unmasked l's (strided), unroll x2, 10*tanh -> us
  // (us pre-filled with NEGV for masked l's; per-l results order-independent).
  {
    const float4 q4 = *(const float4*)&qps[lane << 2];
    const float4 v4 = *(const float4*)&vps[lane << 2];
    const float* ebase = e2p + ((size_t)b << 8) + (lane << 2);
    int i = w;
    for (; i + 8 < cnt; i += 16) {
      const int l0 = lidx[i], l1 = lidx[i + 8];
      const float4 e40 = *(const float4*)(ebase + ((size_t)l0 << 17));
      const float4 e41 = *(const float4*)(ebase + ((size_t)l1 << 17));
      float s0 = v4.x * ftanh(q4.x + e40.x) + v4.y * ftanh(q4.y + e40.y)
               + v4.z * ftanh(q4.z + e40.z) + v4.w * ftanh(q4.w + e40.w);
      float s1 = v4.x * ftanh(q4.x + e41.x) + v4.y * ftanh(q4.y + e41.y)
               + v4.z * ftanh(q4.z + e41.z) + v4.w * ftanh(q4.w + e41.w);
#pragma unroll
      for (int off = 32; off; off >>= 1) {
        s0 += __shfl_xor(s0, off, 64);
        s1 += __shfl_xor(s1, off, 64);
      }
      if (lane == 0) {
        us[l0] = 10.0f * ftanh(s0);
        us[l1] = 10.0f * ftanh(s1);
      }
    }
    if (i < cnt) {
      const int l = lidx[i];
      const float4 e4 = *(const float4*)(ebase + ((size_t)l << 17));
      float s = v4.x * ftanh(q4.x + e4.x) + v4.y * ftanh(q4.y + e4.y)
              + v4.z * ftanh(q4.z + e4.z) + v4.w * ftanh(q4.w + e4.w);
#pragma unroll
      for (int off = 32; off; off >>= 1) s += __shfl_xor(s, off, 64);
      if (lane == 0) us[l] = 10.0f * ftanh(s);
    }
  }
  __syncthreads();
  if (tid < 64) {
    const float xv = us[tid];
    float mx = xv;
#pragma unroll
    for (int off = 32; off; off >>= 1) mx = fmaxf(mx, __shfl_xor(mx, off, 64));
    const float sh = xv - mx;
    const float ev = __expf(sh);
    float sum = ev;
#pragma unroll
    for (int off = 32; off; off >>= 1) sum += __shfl_xor(sum, off, 64);
    const float lp = sh - __logf(sum);
    out_logp[((size_t)b << 12) + (t << 6) + tid] = lp;
    float bv = lp; int bi = tid;
#pragma unroll
    for (int off = 32; off; off >>= 1) {
      const float ov = __shfl_xor(bv, off, 64);
      const int   oi = __shfl_xor(bi, off, 64);
      if (ov > bv || (ov == bv && oi < bi)) { bv = ov; bi = oi; }
    }
    if (tid == 0) { idxb[b] = bi; out_sel[(b << 6) + t] = (float)bi; bsel = bi; }
  }
  __syncthreads();
  if (tid < 256) xb[(b << 8) + tid] = emb[(((size_t)(bsel << 9) + b) << 8) + tid];
}

// ---------------------------------------------------------------------------
// setup kernels
// ---------------------------------------------------------------------------
__global__ __launch_bounds__(256) void init_k(
    const float* __restrict__ dec, const float* __restrict__ h0,
    const float* __restrict__ c0, float* __restrict__ xb,
    float* __restrict__ hb, float* __restrict__ cb,
    unsigned long long* __restrict__ mask, int* __restrict__ idxb)
{
  const int i = blockIdx.x * 256 + threadIdx.x;
  xb[i] = dec[i]; hb[i] = h0[i]; cb[i] = c0[i];
  if (i < 512) { mask[i] = 0ULL; idxb[i] = -1; }
}

// Wcat[n][k], n=4*j+p interleaved (p in {i,f,g,o}), k = [x-part | h-part]
__global__ __launch_bounds__(256) void prep_wcat_k(
    const float* __restrict__ Wih, const float* __restrict__ Whh,
    const float* __restrict__ bih, const float* __restrict__ bhh,
    float* __restrict__ Wcat, float* __restrict__ bcat)
{
  const int id = blockIdx.x * 256 + threadIdx.x;
  const int n = id >> 9, k = id & 511;
  const int r = ((n & 3) << 8) + (n >> 2);
  Wcat[id] = (k < 256) ? Wih[(r << 8) + k] : Whh[(r << 8) + (k - 256)];
  if (id < 1024) {
    const int rr = ((id & 3) << 8) + (id >> 2);
    bcat[id] = bih[rr] + bhh[rr];
  }
}

// Wfused = Wq_g @ Wm (256x320), bfused = Wq_g @ bm + bq_g
__global__ __launch_bounds__(256) void prep_wfused_k(
    const float* __restrict__ Wqg, const float* __restrict__ Wm,
    const float* __restrict__ bm, const float* __restrict__ bqg,
    float* __restrict__ Wf, float* __restrict__ bf)
{
  const int id = blockIdx.x * 256 + threadIdx.x;  // 81920
  const int o = id / 320, j = id % 320;
  float acc = 0.f;
  for (int tt = 0; tt < 256; ++tt) acc += Wqg[(o << 8) + tt] * Wm[tt * 320 + j];
  Wf[id] = acc;
  if (id < 256) {
    float a2 = 0.f;
    for (int tt = 0; tt < 256; ++tt) a2 += Wqg[(id << 8) + tt] * bm[tt];
    bf[id] = a2 + bqg[id];
  }
}

// Wq1T4: packed transpose of Wfused[:, :256] for coalesced float4 matvec.
__global__ __launch_bounds__(256) void prep_wq1t4_k(
    const float* __restrict__ Wf, float* __restrict__ Wq1T4)
{
  const int id = blockIdx.x * 256 + threadIdx.x;  // 65536
  const int k = id >> 8, o = id & 255;
  Wq1T4[((k >> 2) << 10) + (o << 2) + (k & 3)] = Wf[o * 320 + k];
}

// Wqp4: packed transpose of raw Wqp for coalesced float4 matvec.
__global__ __launch_bounds__(256) void prep_wqp4_k(
    const float* __restrict__ Wqp, float* __restrict__ Wqp4)
{
  const int id = blockIdx.x * 256 + threadIdx.x;  // 65536
  const int k = id >> 8, o = id & 255;
  Wqp4[((k >> 2) << 10) + (o << 2) + (k & 3)] = Wqp[(o << 8) + k];
}

// qcour[b,o] = bfused[o] + sum_{k<64} Wfused[o][256+k] * cour[b][k]
__global__ __launch_bounds__(256) void prep_qcour_k(
    const float* __restrict__ Wf, const float* __restrict__ bf,
    const float* __restrict__ cour, float* __restrict__ qcour)
{
  const int b = blockIdx.x, o = threadIdx.x;
  __shared__ float cs[64];
  if (o < 64) cs[o] = cour[(b << 6) + o];
  __syncthreads();
  float acc = bf[o];
#pragma unroll 8
  for (int k = 0; k < 64; ++k) acc += Wf[o * 320 + 256 + k] * cs[k];
  qcour[(b << 8) + o] = acc;
}

// W2 rows 0..255 = Wrg, rows 256..511 = Wrp; b2 = {brg | brp}
__global__ __launch_bounds__(256) void prep_w2copy_k(
    const float* __restrict__ Wrg, const float* __restrict__ Wrp,
    const float* __restrict__ brg, const float* __restrict__ brp,
    float* __restrict__ W2, float* __restrict__ b2)
{
  const int id = blockIdx.x * 256 + threadIdx.x;   // 131072
  W2[id] = (id < 65536) ? Wrg[id] : Wrp[id - 65536];
  if (id < 256) b2[id] = brg[id];
  else if (id < 512) b2[id] = brp[id - 256];
}

// ---------------------------------------------------------------------------
extern "C" void kernel_launch(void* const* d_in, const int* in_sizes, int n_in,
                              void* d_out, int out_size, void* d_ws, size_t ws_size,
                              hipStream_t stream)
{
  const float* dec   = (const float*)d_in[0];
  const float* emb   = (const float*)d_in[1];
  const float* h0    = (const float*)d_in[2];
  const float* c0    = (const float*)d_in[3];
  const float* ctxin = (const float*)d_in[4];
  const float* cour  = (const float*)d_in[5];
  const float* Wih   = (const float*)d_in[7];
  const float* Whh   = (const float*)d_in[8];
  const float* bih   = (const float*)d_in[9];
  const float* bhh   = (const float*)d_in[10];
  const float* Wm    = (const float*)d_in[11];
  const float* bm    = (const float*)d_in[12];
  const float* Wqp   = (const float*)d_in[13];
  const float* bqp   = (const float*)d_in[14];
  const float* Wrp   = (const float*)d_in[15];
  const float* brp   = (const float*)d_in[16];
  const float* vp    = (const float*)d_in[17];
  const float* Wqg   = (const float*)d_in[18];
  const float* bqg   = (const float*)d_in[19];
  const float* Wrg   = (const float*)d_in[20];
  const float* brg   = (const float*)d_in[21];
  const float* vg    = (const float*)d_in[22];

  float* ws = (float*)d_ws;
  float* e2g    = ws + 0;         // 8388608
  float* e2p    = ws + 8388608;   // 8388608
  float* W2     = ws + 16777216;  // 131072
  float* b2     = ws + 16908288;  // 512
  float* Wcat   = ws + 16908800;  // 524288
  float* bcat   = ws + 17433088;  // 1024
  float* Wfused = ws + 17434112;  // 81920
  float* bfused = ws + 17516032;  // 256
  float* Wq1T4  = ws + 17516288;  // 65536
  float* Wqp4   = ws + 17581824;  // 65536
  float* qcour  = ws + 17647360;  // 131072
  float* hb0    = ws + 17778432;  // 131072
  float* hb1    = ws + 17909504;  // 131072
  float* cb0    = ws + 18040576;  // 131072
  float* cb1    = ws + 18171648;  // 131072
  float* xb     = ws + 18302720;  // 131072
  unsigned long long* maskb = (unsigned long long*)(ws + 18433792); // 512 u64
  int* idxb     = (int*)(ws + 18434816);                            // 512

  float* out_logp = (float*)d_out;            // [B][64][64]
  float* out_sel  = (float*)d_out + 2097152;  // [B][64]

  // ---- setup ----
  init_k<<<512, 256, 0, stream>>>(dec, h0, c0, xb, hb0, cb0, maskb, idxb);
  prep_wcat_k<<<2048, 256, 0, stream>>>(Wih, Whh, bih, bhh, Wcat, bcat);
  prep_wfused_k<<<320, 256, 0, stream>>>(Wqg, Wm, bm, bqg, Wfused, bfused);
  prep_wq1t4_k<<<256, 256, 0, stream>>>(Wfused, Wq1T4);
  prep_wqp4_k<<<256, 256, 0, stream>>>(Wqp, Wqp4);
  prep_qcour_k<<<512, 256, 0, stream>>>(Wfused, bfused, cour, qcour);
  prep_w2copy_k<<<512, 256, 0, stream>>>(Wrg, Wrp, brg, brp, W2, b2);
  gemm2_k<<<dim3(256, 4), 256, 0, stream>>>(ctxin, W2, b2, e2g, e2p);

  // ---- 64 sequential steps, 2 kernels each ----
  for (int t = 0; t < 64; ++t) {
    float* hcur = (t & 1) ? hb1 : hb0;
    float* hnew = (t & 1) ? hb0 : hb1;
    float* ccur = (t & 1) ? cb1 : cb0;
    float* cnew = (t & 1) ? cb0 : cb1;
    gates_lstm_k<<<dim3(16, 32), 256, 0, stream>>>(xb, hcur, Wcat, bcat,
                                                   ccur, cnew, hnew);
    step_attn_k<<<512, 512, 0, stream>>>(hnew, e2g, e2p, Wq1T4, Wqp4, qcour,
                                         bqp, vg, vp, maskb, idxb, emb,
                                         out_logp, out_sel, xb, t);
  }
}